// Round 5
// baseline (367.254 us; speedup 1.0000x reference)
//
#include <hip/hip_runtime.h>
#include <hip/hip_bf16.h>
#include <math.h>

// MoE noisy-top1 gating:
//   clean = input @ w_gate            [N,3]
//   raw   = input @ w_noise           [N,3]
//   std   = softplus(raw) + 0.2
//   logit = clean + noise * std
//   out   = argmax_e(logit)  (int32, lowest index on ties)
//
// N=262144 tokens, D=256, E=3. Memory floor ~45 us (L3-resident 260 MB).
//
// R1: one wave/token, 64-lane butterflies -> 216 us (latency-bound).
// R2: 8 lanes/token, 3-step butterfly -> ~140 us.
// R3: weight-load hoist -> NEUTRAL (~145 us). L1 weight traffic not the issue.
// R4: single upfront vmem batch (one drain) + weights in LDS -> ~110 us. WIN.
// R5: amortize per-wave fixed costs + DS-pipe: 16 tokens/wave (2 groups),
//     p-loop reads weights from LDS once and applies to BOTH groups
//     (ds_reads/token 6 -> 3); prologue/barrier/kernarg per token halved.
//     Math order per token bitwise identical to R2-R4.

#define NTOK 262144
#define DDIM 256
#define NEXP 3
#define NOISE_EPS 0.2f

__device__ __forceinline__ float softplus_stable(float x) {
    // log(1+exp(x)) = max(x,0) + log1p(exp(-|x|))   (matches jax.nn.softplus)
    return fmaxf(x, 0.0f) + log1pf(expf(-fabsf(x)));
}

__global__ __launch_bounds__(256) void moe_gate_kernel(
    const float* __restrict__ input,    // [N, D]
    const float* __restrict__ w_gate,   // [D, E] row-major
    const float* __restrict__ w_noise,  // [D, E] row-major
    const float* __restrict__ noise,    // [N, E]
    int* __restrict__ out)              // [N]
{
    // Weights in LDS: 192 float4 each (D*E = 768 floats), 6 KB total.
    __shared__ float4 sWg[192];
    __shared__ float4 sWn[192];

    const int tid = threadIdx.x;
    if (tid < 192) {
        sWg[tid] = ((const float4*)w_gate)[tid];
        sWn[tid] = ((const float4*)w_noise)[tid];
    }

    const int lane = tid & 63;
    const int s    = lane & 7;    // sublane within token: dims 32p+4s..+3
    const int g    = lane >> 3;   // token slot within group (8 tokens/group)

    const int waveId = blockIdx.x * 4 + (tid >> 6);
    const int t0     = waveId * 16 + g;   // group-0 token
    const int t1     = t0 + 8;            // group-1 token

    // Preload both row tiles upfront: 16 float4s/lane = 16 KB/wave in flight,
    // everything drains once at the barrier below.
    const float4* in4  = (const float4*)input;
    const float4* row0 = in4 + (size_t)t0 * 64 + s;
    const float4* row1 = in4 + (size_t)t1 * 64 + s;
    float4 x0[8], x1[8];
    #pragma unroll
    for (int p = 0; p < 8; ++p) x0[p] = row0[p * 8];
    #pragma unroll
    for (int p = 0; p < 8; ++p) x1[p] = row1[p * 8];

    const float nz00 = noise[(size_t)t0 * NEXP + 0];
    const float nz01 = noise[(size_t)t0 * NEXP + 1];
    const float nz02 = noise[(size_t)t0 * NEXP + 2];
    const float nz10 = noise[(size_t)t1 * NEXP + 0];
    const float nz11 = noise[(size_t)t1 * NEXP + 1];
    const float nz12 = noise[(size_t)t1 * NEXP + 2];

    __syncthreads();   // weights visible; all vmem drained here (once)

    float g00 = 0.f, g01 = 0.f, g02 = 0.f, n00 = 0.f, n01 = 0.f, n02 = 0.f;
    float g10 = 0.f, g11 = 0.f, g12 = 0.f, n10 = 0.f, n11 = 0.f, n12 = 0.f;

    #pragma unroll
    for (int p = 0; p < 8; ++p) {
        // Weights for this lane's 4 dims of pass p — read from LDS once,
        // applied to BOTH token groups (conflict-free broadcast layout).
        const int wi = 3 * (p * 8 + s);
        const float4 wg0 = sWg[wi + 0];  // {d0e0 d0e1 d0e2 d1e0}
        const float4 wg1 = sWg[wi + 1];  // {d1e1 d1e2 d2e0 d2e1}
        const float4 wg2 = sWg[wi + 2];  // {d2e2 d3e0 d3e1 d3e2}
        const float4 wn0 = sWn[wi + 0];
        const float4 wn1 = sWn[wi + 1];
        const float4 wn2 = sWn[wi + 2];

        // Identical FMA nesting / p-ascending order as R2-R4 (bitwise same).
        g00 = fmaf(x0[p].x, wg0.x, fmaf(x0[p].y, wg0.w, fmaf(x0[p].z, wg1.z, fmaf(x0[p].w, wg2.y, g00))));
        g01 = fmaf(x0[p].x, wg0.y, fmaf(x0[p].y, wg1.x, fmaf(x0[p].z, wg1.w, fmaf(x0[p].w, wg2.z, g01))));
        g02 = fmaf(x0[p].x, wg0.z, fmaf(x0[p].y, wg1.y, fmaf(x0[p].z, wg2.x, fmaf(x0[p].w, wg2.w, g02))));
        n00 = fmaf(x0[p].x, wn0.x, fmaf(x0[p].y, wn0.w, fmaf(x0[p].z, wn1.z, fmaf(x0[p].w, wn2.y, n00))));
        n01 = fmaf(x0[p].x, wn0.y, fmaf(x0[p].y, wn1.x, fmaf(x0[p].z, wn1.w, fmaf(x0[p].w, wn2.z, n01))));
        n02 = fmaf(x0[p].x, wn0.z, fmaf(x0[p].y, wn1.y, fmaf(x0[p].z, wn2.x, fmaf(x0[p].w, wn2.w, n02))));

        g10 = fmaf(x1[p].x, wg0.x, fmaf(x1[p].y, wg0.w, fmaf(x1[p].z, wg1.z, fmaf(x1[p].w, wg2.y, g10))));
        g11 = fmaf(x1[p].x, wg0.y, fmaf(x1[p].y, wg1.x, fmaf(x1[p].z, wg1.w, fmaf(x1[p].w, wg2.z, g11))));
        g12 = fmaf(x1[p].x, wg0.z, fmaf(x1[p].y, wg1.y, fmaf(x1[p].z, wg2.x, fmaf(x1[p].w, wg2.w, g12))));
        n10 = fmaf(x1[p].x, wn0.x, fmaf(x1[p].y, wn0.w, fmaf(x1[p].z, wn1.z, fmaf(x1[p].w, wn2.y, n10))));
        n11 = fmaf(x1[p].x, wn0.y, fmaf(x1[p].y, wn1.x, fmaf(x1[p].z, wn1.w, fmaf(x1[p].w, wn2.z, n11))));
        n12 = fmaf(x1[p].x, wn0.z, fmaf(x1[p].y, wn1.y, fmaf(x1[p].z, wn2.x, fmaf(x1[p].w, wn2.w, n12))));
    }

    // 3-step butterfly across the 8 sublanes; both groups' 8 tokens each
    // reduced simultaneously. Same tree as R2-R4.
    #pragma unroll
    for (int st = 1; st < 8; st <<= 1) {
        g00 += __shfl_xor(g00, st);
        g01 += __shfl_xor(g01, st);
        g02 += __shfl_xor(g02, st);
        n00 += __shfl_xor(n00, st);
        n01 += __shfl_xor(n01, st);
        n02 += __shfl_xor(n02, st);
        g10 += __shfl_xor(g10, st);
        g11 += __shfl_xor(g11, st);
        g12 += __shfl_xor(g12, st);
        n10 += __shfl_xor(n10, st);
        n11 += __shfl_xor(n11, st);
        n12 += __shfl_xor(n12, st);
    }

    // Epilogue: all lanes compute (no divergence); s==0 stores both tokens.
    {
        const float l0 = fmaf(nz00, softplus_stable(n00) + NOISE_EPS, g00);
        const float l1 = fmaf(nz01, softplus_stable(n01) + NOISE_EPS, g01);
        const float l2 = fmaf(nz02, softplus_stable(n02) + NOISE_EPS, g02);
        int best = 0;
        float bv = l0;
        if (l1 > bv) { bv = l1; best = 1; }
        if (l2 > bv) { bv = l2; best = 2; }
        if (s == 0) out[t0] = best;
    }
    {
        const float l0 = fmaf(nz10, softplus_stable(n10) + NOISE_EPS, g10);
        const float l1 = fmaf(nz11, softplus_stable(n11) + NOISE_EPS, g11);
        const float l2 = fmaf(nz12, softplus_stable(n12) + NOISE_EPS, g12);
        int best = 0;
        float bv = l0;
        if (l1 > bv) { bv = l1; best = 1; }
        if (l2 > bv) { bv = l2; best = 2; }
        if (s == 0) out[t1] = best;
    }
}

extern "C" void kernel_launch(void* const* d_in, const int* in_sizes, int n_in,
                              void* d_out, int out_size, void* d_ws, size_t ws_size,
                              hipStream_t stream) {
    const float* input   = (const float*)d_in[0];
    const float* w_gate  = (const float*)d_in[1];
    const float* w_noise = (const float*)d_in[2];
    const float* noise   = (const float*)d_in[3];
    int* out = (int*)d_out;

    // 4096 blocks x 256 thr = 16384 waves x 16 tokens = 262144.
    dim3 grid(4096), block(256);
    moe_gate_kernel<<<grid, block, 0, stream>>>(input, w_gate, w_noise, noise, out);
}

// Round 6
// 338.625 us; speedup vs baseline: 1.0845x; 1.0845x over previous
//
#include <hip/hip_runtime.h>
#include <hip/hip_bf16.h>
#include <math.h>

// MoE noisy-top1 gating:
//   clean = input @ w_gate            [N,3]
//   raw   = input @ w_noise           [N,3]
//   std   = softplus(raw) + 0.2
//   logit = clean + noise * std
//   out   = argmax_e(logit)  (int32, lowest index on ties)
//
// N=262144 tokens, D=256, E=3.
//
// R1: one wave/token, 64-lane butterflies -> 216 us (latency-bound).
// R2: 8 lanes/token, 3-step butterfly -> ~140 us.
// R3: weight-load hoist -> NEUTRAL. R4: one vmem drain + weights in LDS ->
// ~110 us WIN. R5: 16 tok/wave (DS-pipe + fixed-cost amortize) -> NEUTRAL.
// Conclusion: per-pipe budgets (VALU 9us, DS 20us, HBM-read 43us) don't sum
// to 110us. Missing term: the harness's 1 GiB 0xAA workspace poison leaves
// the 256 MiB L3 full of DIRTY lines; our cached reads allocate into L3 and
// force ~250 MB of dirty writebacks during the kernel -> ~520 MB effective
// traffic. R6: NON-TEMPORAL loads for input/noise (read-once data, L3 gets
// clobbered by the poison every iteration anyway) -> no L3 allocation, no
// eviction writebacks. nt store for out (no RFO). Weights stay cached.
// Math bitwise identical to R4.

#define NTOK 262144
#define DDIM 256
#define NEXP 3
#define NOISE_EPS 0.2f

typedef float vfloat4 __attribute__((ext_vector_type(4)));

__device__ __forceinline__ vfloat4 ntload4(const vfloat4* p) {
    return __builtin_nontemporal_load(p);
}

__device__ __forceinline__ float softplus_stable(float x) {
    // log(1+exp(x)) = max(x,0) + log1p(exp(-|x|))   (matches jax.nn.softplus)
    return fmaxf(x, 0.0f) + log1pf(expf(-fabsf(x)));
}

__global__ __launch_bounds__(256) void moe_gate_kernel(
    const float* __restrict__ input,    // [N, D]
    const float* __restrict__ w_gate,   // [D, E] row-major
    const float* __restrict__ w_noise,  // [D, E] row-major
    const float* __restrict__ noise,    // [N, E]
    int* __restrict__ out)              // [N]
{
    // Weights in LDS: 192 float4 each (D*E = 768 floats), 6 KB total.
    // These ARE cached (hot across all 8192 blocks; 6 KB lives in L2).
    __shared__ float4 sWg[192];
    __shared__ float4 sWn[192];

    const int tid = threadIdx.x;
    if (tid < 192) {
        sWg[tid] = ((const float4*)w_gate)[tid];
        sWn[tid] = ((const float4*)w_noise)[tid];
    }

    const int lane = tid & 63;
    const int s    = lane & 7;    // sublane within token: dims 32p+4s..+3
    const int g    = lane >> 3;   // token slot within wave (8 tokens/wave)

    const int waveId = blockIdx.x * 4 + (tid >> 6);
    const int t      = waveId * 8 + g;          // this lane's token

    // Preload the entire row tile non-temporally: 8 float4s (dims 32p+4s..+3),
    // issued back-to-back -> 8 KB/wave in flight, one drain at the barrier.
    // nt: do NOT allocate in L2/L3 -> no dirty-poison evictions.
    const vfloat4* in4  = (const vfloat4*)input;
    const vfloat4* rowp = in4 + (size_t)t * 64 + s;
    vfloat4 x[8];
    #pragma unroll
    for (int p = 0; p < 8; ++p) x[p] = ntload4(rowp + p * 8);

    // Noise: read-once, nt as well.
    const float* nz = noise + (size_t)t * NEXP;
    const float nz0 = __builtin_nontemporal_load(nz + 0);
    const float nz1 = __builtin_nontemporal_load(nz + 1);
    const float nz2 = __builtin_nontemporal_load(nz + 2);

    __syncthreads();   // weights visible; all vmem drained here (once)

    float g0 = 0.f, g1 = 0.f, g2 = 0.f;
    float n0 = 0.f, n1 = 0.f, n2 = 0.f;

    #pragma unroll
    for (int p = 0; p < 8; ++p) {
        // Weights for this lane's 4 dims of pass p (LDS, conflict-free:
        // 8 unique addresses spanning all 32 banks, 8-lane broadcast each).
        const int wi = 3 * (p * 8 + s);
        const float4 wg0 = sWg[wi + 0];  // {d0e0 d0e1 d0e2 d1e0}
        const float4 wg1 = sWg[wi + 1];  // {d1e1 d1e2 d2e0 d2e1}
        const float4 wg2 = sWg[wi + 2];  // {d2e2 d3e0 d3e1 d3e2}
        const float4 wn0 = sWn[wi + 0];
        const float4 wn1 = sWn[wi + 1];
        const float4 wn2 = sWn[wi + 2];

        // Identical FMA nesting and p-ascending order as R2-R5 (bitwise same).
        g0 = fmaf(x[p].x, wg0.x, fmaf(x[p].y, wg0.w, fmaf(x[p].z, wg1.z, fmaf(x[p].w, wg2.y, g0))));
        g1 = fmaf(x[p].x, wg0.y, fmaf(x[p].y, wg1.x, fmaf(x[p].z, wg1.w, fmaf(x[p].w, wg2.z, g1))));
        g2 = fmaf(x[p].x, wg0.z, fmaf(x[p].y, wg1.y, fmaf(x[p].z, wg2.x, fmaf(x[p].w, wg2.w, g2))));
        n0 = fmaf(x[p].x, wn0.x, fmaf(x[p].y, wn0.w, fmaf(x[p].z, wn1.z, fmaf(x[p].w, wn2.y, n0))));
        n1 = fmaf(x[p].x, wn0.y, fmaf(x[p].y, wn1.x, fmaf(x[p].z, wn1.w, fmaf(x[p].w, wn2.z, n1))));
        n2 = fmaf(x[p].x, wn0.z, fmaf(x[p].y, wn1.y, fmaf(x[p].z, wn2.x, fmaf(x[p].w, wn2.w, n2))));
    }

    // Reduce across the 8 sublanes of each token (3 butterfly steps, all 8
    // tokens of the wave simultaneously). Same tree as R2-R5.
    #pragma unroll
    for (int st = 1; st < 8; st <<= 1) {
        g0 += __shfl_xor(g0, st);
        g1 += __shfl_xor(g1, st);
        g2 += __shfl_xor(g2, st);
        n0 += __shfl_xor(n0, st);
        n1 += __shfl_xor(n1, st);
        n2 += __shfl_xor(n2, st);
    }

    // Epilogue: all lanes compute (no divergence); s==0 stores.
    const float l0 = fmaf(nz0, softplus_stable(n0) + NOISE_EPS, g0);
    const float l1 = fmaf(nz1, softplus_stable(n1) + NOISE_EPS, g1);
    const float l2 = fmaf(nz2, softplus_stable(n2) + NOISE_EPS, g2);

    int best = 0;
    float bv = l0;
    if (l1 > bv) { bv = l1; best = 1; }
    if (l2 > bv) { bv = l2; best = 2; }
    if (s == 0) __builtin_nontemporal_store(best, &out[t]);
}

extern "C" void kernel_launch(void* const* d_in, const int* in_sizes, int n_in,
                              void* d_out, int out_size, void* d_ws, size_t ws_size,
                              hipStream_t stream) {
    const float* input   = (const float*)d_in[0];
    const float* w_gate  = (const float*)d_in[1];
    const float* w_noise = (const float*)d_in[2];
    const float* noise   = (const float*)d_in[3];
    int* out = (int*)d_out;

    // 8192 blocks x 256 thr = 32768 waves x 8 tokens = 262144.
    dim3 grid(8192), block(256);
    moe_gate_kernel<<<grid, block, 0, stream>>>(input, w_gate, w_noise, noise, out);
}

// Round 7
// 338.141 us; speedup vs baseline: 1.0861x; 1.0014x over previous
//
#include <hip/hip_runtime.h>
#include <hip/hip_bf16.h>
#include <math.h>

// MoE noisy-top1 gating:
//   clean = input @ w_gate            [N,3]
//   raw   = input @ w_noise           [N,3]
//   std   = softplus(raw) + 0.2
//   logit = clean + noise * std
//   out   = argmax_e(logit)  (int32, lowest index on ties)
//
// N=262144 tokens, D=256, E=3.
//
// R1 216us -> R2 140 -> R4 (one vmem drain + weights in LDS) 110 ->
// R6 (__builtin_nontemporal_load) 88us.
// Model: the harness's 1 GiB 0xAA ws-poison leaves the memory-side MALL
// (Infinity Cache) full of DIRTY lines. Every input-read miss that ALLOCATES
// evicts a dirty poison line -> 64B writeback per 64B read. 268 rd + 256 wb
// = 524 MB ~= 87us at 6 TB/s = exactly R6's measured kernel time. The nt
// flag from __builtin_nontemporal_load evidently only affected L2.
// R7: raw buffer loads with explicit cpol aux = SC0|NT|SC1 (1|2|16 = 19) —
// non-temporal + system scope at every cache level. If MALL honors
// instruction-level no-allocate, the poison-writeback tax (~45us) vanishes.
// Coherence-safe: MALL is memory-side (all HBM traffic passes through it);
// L2 is flushed at dispatch boundaries. Math bitwise identical to R2-R6.

#define NTOK 262144
#define DDIM 256
#define NEXP 3
#define NOISE_EPS 0.2f

typedef int   int32x4_t __attribute__((ext_vector_type(4)));
typedef float vfloat4   __attribute__((ext_vector_type(4)));

// CK-style raw intrinsic declaration (llvm.amdgcn.raw.buffer.load).
__device__ vfloat4 llvm_amdgcn_raw_buffer_load_fp32x4(
    int32x4_t srsrc, int voffset, int soffset, int cpol)
    __asm("llvm.amdgcn.raw.buffer.load.v4f32");

#define CPOL_STREAM 19  // SC0(1) | NT(2) | SC1(16): nt + system scope

__device__ __forceinline__ float softplus_stable(float x) {
    // log(1+exp(x)) = max(x,0) + log1p(exp(-|x|))   (matches jax.nn.softplus)
    return fmaxf(x, 0.0f) + log1pf(expf(-fabsf(x)));
}

__global__ __launch_bounds__(256) void moe_gate_kernel(
    const float* __restrict__ input,    // [N, D]
    const float* __restrict__ w_gate,   // [D, E] row-major
    const float* __restrict__ w_noise,  // [D, E] row-major
    const float* __restrict__ noise,    // [N, E]
    int* __restrict__ out)              // [N]
{
    // Weights in LDS: 192 float4 each (D*E = 768 floats), 6 KB total.
    __shared__ float4 sWg[192];
    __shared__ float4 sWn[192];

    const int tid = threadIdx.x;
    if (tid < 192) {
        sWg[tid] = ((const float4*)w_gate)[tid];
        sWn[tid] = ((const float4*)w_noise)[tid];
    }

    const int lane = tid & 63;
    const int s    = lane & 7;    // sublane within token: dims 32p+4s..+3
    const int g    = lane >> 3;   // token slot within wave (8 tokens/wave)

    const int waveId = blockIdx.x * 4 + (tid >> 6);
    const int t      = waveId * 8 + g;          // this lane's token

    // SRD over the input buffer (256 MB -> 32-bit offsets fit).
    union { const float* p; unsigned int u32[2]; } pb;
    pb.p = input;
    int32x4_t srd;
    srd.x = (int)pb.u32[0];
    srd.y = (int)pb.u32[1];       // 48-bit VA: bits 47:32 land in word1[15:0]
    srd.z = (int)0x10000000;      // num_records = 268435456 bytes
    srd.w = (int)0x00020000;      // raw untyped dword access

    // Preload the entire row tile with streaming buffer loads: 8 float4s
    // (dims 32p+4s..+3), issued back-to-back, one drain at the barrier.
    const int base = t * 1024 + s * 16;   // byte offset of this lane's chunk
    vfloat4 x[8];
    #pragma unroll
    for (int p = 0; p < 8; ++p)
        x[p] = llvm_amdgcn_raw_buffer_load_fp32x4(srd, base + p * 128, 0, CPOL_STREAM);

    // Noise: read-once, nt (tiny: 3 MB total).
    const float* nz = noise + (size_t)t * NEXP;
    const float nz0 = __builtin_nontemporal_load(nz + 0);
    const float nz1 = __builtin_nontemporal_load(nz + 1);
    const float nz2 = __builtin_nontemporal_load(nz + 2);

    __syncthreads();   // weights visible; all vmem drained here (once)

    float g0 = 0.f, g1 = 0.f, g2 = 0.f;
    float n0 = 0.f, n1 = 0.f, n2 = 0.f;

    #pragma unroll
    for (int p = 0; p < 8; ++p) {
        // Weights for this lane's 4 dims of pass p (LDS, conflict-free
        // broadcast layout: 8 unique addresses spanning all 32 banks).
        const int wi = 3 * (p * 8 + s);
        const float4 wg0 = sWg[wi + 0];  // {d0e0 d0e1 d0e2 d1e0}
        const float4 wg1 = sWg[wi + 1];  // {d1e1 d1e2 d2e0 d2e1}
        const float4 wg2 = sWg[wi + 2];  // {d2e2 d3e0 d3e1 d3e2}
        const float4 wn0 = sWn[wi + 0];
        const float4 wn1 = sWn[wi + 1];
        const float4 wn2 = sWn[wi + 2];

        // Identical FMA nesting and p-ascending order as R2-R6 (bitwise same).
        g0 = fmaf(x[p].x, wg0.x, fmaf(x[p].y, wg0.w, fmaf(x[p].z, wg1.z, fmaf(x[p].w, wg2.y, g0))));
        g1 = fmaf(x[p].x, wg0.y, fmaf(x[p].y, wg1.x, fmaf(x[p].z, wg1.w, fmaf(x[p].w, wg2.z, g1))));
        g2 = fmaf(x[p].x, wg0.z, fmaf(x[p].y, wg1.y, fmaf(x[p].z, wg2.x, fmaf(x[p].w, wg2.w, g2))));
        n0 = fmaf(x[p].x, wn0.x, fmaf(x[p].y, wn0.w, fmaf(x[p].z, wn1.z, fmaf(x[p].w, wn2.y, n0))));
        n1 = fmaf(x[p].x, wn0.y, fmaf(x[p].y, wn1.x, fmaf(x[p].z, wn1.w, fmaf(x[p].w, wn2.z, n1))));
        n2 = fmaf(x[p].x, wn0.z, fmaf(x[p].y, wn1.y, fmaf(x[p].z, wn2.x, fmaf(x[p].w, wn2.w, n2))));
    }

    // Reduce across the 8 sublanes of each token (3 butterfly steps, all 8
    // tokens of the wave simultaneously). Same tree as R2-R6.
    #pragma unroll
    for (int st = 1; st < 8; st <<= 1) {
        g0 += __shfl_xor(g0, st);
        g1 += __shfl_xor(g1, st);
        g2 += __shfl_xor(g2, st);
        n0 += __shfl_xor(n0, st);
        n1 += __shfl_xor(n1, st);
        n2 += __shfl_xor(n2, st);
    }

    // Epilogue: all lanes compute (no divergence); s==0 stores.
    const float l0 = fmaf(nz0, softplus_stable(n0) + NOISE_EPS, g0);
    const float l1 = fmaf(nz1, softplus_stable(n1) + NOISE_EPS, g1);
    const float l2 = fmaf(nz2, softplus_stable(n2) + NOISE_EPS, g2);

    int best = 0;
    float bv = l0;
    if (l1 > bv) { bv = l1; best = 1; }
    if (l2 > bv) { bv = l2; best = 2; }
    if (s == 0) __builtin_nontemporal_store(best, &out[t]);
}

extern "C" void kernel_launch(void* const* d_in, const int* in_sizes, int n_in,
                              void* d_out, int out_size, void* d_ws, size_t ws_size,
                              hipStream_t stream) {
    const float* input   = (const float*)d_in[0];
    const float* w_gate  = (const float*)d_in[1];
    const float* w_noise = (const float*)d_in[2];
    const float* noise   = (const float*)d_in[3];
    int* out = (int*)d_out;

    // 8192 blocks x 256 thr = 32768 waves x 8 tokens = 262144.
    dim3 grid(8192), block(256);
    moe_gate_kernel<<<grid, block, 0, stream>>>(input, w_gate, w_noise, noise, out);
}